// Round 3
// baseline (193.073 us; speedup 1.0000x reference)
//
#include <hip/hip_runtime.h>
#include <hip/hip_bf16.h>

// B=1024, N(nodes)=128, H=128, D=8
// out = [f_out (B*N)] ++ [g_out (B*N*D)], fp32
//
// Per node i, combined weight Wt_i[c][n] (c<1024: g cols h*8+d; c>=1024: f cols h),
// pre-transposed+bf16 in d_ws. Main kernel: x(128 rows)@Wt_i via mfma_f32_16x16x32_bf16,
// fused ELU + H-reduction epilogue in registers.
//
// R3: A-fragments in registers (xs LDS removed -> 16.5 KB LDS, 4 blocks/CU),
// deferred cross-lane reductions (shuffles once at writeout, not per-ct),
// prepass rewritten: no-LDS register transpose, 9344 blocks, coalesced reads.

typedef unsigned short u16;
typedef __attribute__((ext_vector_type(8))) short bf16x8;
typedef __attribute__((ext_vector_type(8))) short short8;
typedef __attribute__((ext_vector_type(4))) float f32x4;

typedef __attribute__((address_space(1))) const void* gas_ptr;
typedef __attribute__((address_space(3))) void* las_ptr;
#define GLOAD_LDS16(g, l) __builtin_amdgcn_global_load_lds((gas_ptr)(g), (las_ptr)(l), 16, 0, 0)

#define WS_W_ELEMS  ((size_t)128 * 1152 * 128)           // 18,874,368 u16
#define WS_X_ELEMS  ((size_t)1024 * 128)                 // 131,072 u16
#define WS_NEED_BYTES ((WS_W_ELEMS + WS_X_ELEMS) * 2)    // 38,010,880 B

__device__ __forceinline__ u16 f2bf(float f) {
    unsigned int u = __float_as_uint(f);
    u += 0x7fffu + ((u >> 16) & 1u);   // RNE
    return (u16)(u >> 16);
}
__device__ __forceinline__ uint32_t pack2bf(float a, float b) {
    return (uint32_t)f2bf(a) | ((uint32_t)f2bf(b) << 16);
}
__device__ __forceinline__ float elu(float v) {
    return v > 0.f ? v : __expf(v) - 1.f;
}

// ---------- merged pre-pass: register transpose, no LDS ----------
// bx <  8192: g_weight  [i][n][c] -> ws [i][c][n]   (i=bx>>6; ctile=(bx>>4)&3; n0=(bx&15)*8)
// bx <  9216: f_weight  [i][n][h] -> ws [i][1024+h][n]
// bx <  9344: x fp32 -> bf16
__global__ void sde_prepass(const float* __restrict__ fw, const float* __restrict__ gw,
                            const float* __restrict__ x, u16* __restrict__ wsW) {
    const int bx = blockIdx.x;
    const int t  = threadIdx.x;
    if (bx < 8192) {
        const int i  = bx >> 6;
        const int c  = (((bx >> 4) & 3) << 8) + t;     // lane-consecutive column
        const int n0 = (bx & 15) << 3;
        const float* src = gw + (size_t)i * 131072;
        float v[8];
        #pragma unroll
        for (int j = 0; j < 8; ++j) v[j] = src[(size_t)(n0 + j) * 1024 + c];
        short8 o;
        #pragma unroll
        for (int j = 0; j < 8; ++j) o[j] = (short)f2bf(v[j]);
        *(short8*)&wsW[((size_t)i * 1152 + c) * 128 + n0] = o;
    } else if (bx < 9216) {
        const int b2 = bx - 8192;
        const int i  = b2 >> 3;
        const int c  = t & 127;
        const int n0 = (((b2 & 7) << 1) + (t >> 7)) << 3;
        const float* src = fw + (size_t)i * 16384;
        float v[8];
        #pragma unroll
        for (int j = 0; j < 8; ++j) v[j] = src[(size_t)(n0 + j) * 128 + c];
        short8 o;
        #pragma unroll
        for (int j = 0; j < 8; ++j) o[j] = (short)f2bf(v[j]);
        *(short8*)&wsW[((size_t)i * 1152 + 1024 + c) * 128 + n0] = o;
    } else {
        const int tid = (bx - 9216) * 256 + t;         // 32768 threads * float4
        float4 v = ((const float4*)x)[tid];
        ((uint2*)(wsW + WS_W_ELEMS))[tid] = make_uint2(pack2bf(v.x, v.y), pack2bf(v.z, v.w));
    }
}

// ---------- main fused MFMA kernel ----------
// grid 1024; bx&127 = node i (same-node blocks share XCD), bx>>7 = btile (128 rows)
// block 256 (4 waves, rows split 4x1). A-fragments live in registers.
__global__ __launch_bounds__(256, 4) void sde_mfma(
    const u16* __restrict__ wsAll,
    const float* __restrict__ Wf, const float* __restrict__ bfp,
    const float* __restrict__ Wg, const float* __restrict__ bgp,
    float* __restrict__ out)
{
    // Swizzled LDS layout: wst[row][chunk j] (16B chunks, 16/row) holds global chunk j^(row&7).
    __shared__ u16 wst[64 * 128];   // B tile, 16 KB
    __shared__ float wgs[128];
    __shared__ float wfs[128];

    const int t    = threadIdx.x;
    const int bx   = blockIdx.x;
    const int i    = bx & 127;      // XCD-affine: all 8 blocks of node i have bx%8 == i%8
    const int b0   = (bx >> 7) << 7;
    const int w    = t >> 6;
    const int lane = t & 63;
    const int l15  = lane & 15;
    const int quad = lane >> 4;
    const int rl   = lane >> 4;     // row-in-group for staging
    const int j16  = lane & 15;     // chunk for staging
    const int sw   = l15 & 7;       // read-side swizzle

    const u16* wsW = wsAll;
    const u16* wsX = wsAll + WS_W_ELEMS;

    if (t < 128) { wgs[t] = Wg[i * 128 + t]; wfs[t] = Wf[i * 128 + t]; }

    // A-fragments: rows w*32+l15 (+16), k = kk*32 + quad*8 .. +7 — direct global 16B loads
    bf16x8 afrag[2][4];
    {
        const size_t r0 = (size_t)(b0 + w * 32 + l15) * 128 + quad * 8;
        #pragma unroll
        for (int kk = 0; kk < 4; ++kk) {
            afrag[0][kk] = *(const bf16x8*)&wsX[r0 + kk * 32];
            afrag[1][kk] = *(const bf16x8*)&wsX[r0 + 16 * 128 + kk * 32];
        }
    }

    float racc[8], frac[8];
    #pragma unroll
    for (int q = 0; q < 8; ++q) { racc[q] = 0.f; frac[q] = 0.f; }

    for (int ct = 0; ct < 18; ++ct) {
        // stage 64-col weight tile (16 KB, swizzled via per-lane source chunk)
        {
            const char* srcW = (const char*)(wsW + ((size_t)i * 1152 + ct * 64) * 128);
            #pragma unroll
            for (int r = 0; r < 4; ++r) {
                int row = w * 16 + r * 4 + rl;
                int soff = row * 256 + ((j16 ^ (row & 7)) << 4);
                GLOAD_LDS16(srcW + soff, (char*)wst + w * 4096 + r * 1024);
            }
        }
        __syncthreads();

        f32x4 acc[2][4];
        #pragma unroll
        for (int rs = 0; rs < 2; ++rs)
            #pragma unroll
            for (int cs = 0; cs < 4; ++cs)
                acc[rs][cs] = (f32x4){0.f, 0.f, 0.f, 0.f};

        #pragma unroll
        for (int kk = 0; kk < 4; ++kk) {
            const int co = ((kk * 4 + quad) ^ sw) << 3;   // swizzled u16 offset in row
            bf16x8 bv[4];
            #pragma unroll
            for (int cs = 0; cs < 4; ++cs)
                bv[cs] = *(const bf16x8*)&wst[(cs * 16 + l15) * 128 + co];
            #pragma unroll
            for (int cs = 0; cs < 4; ++cs) {
                acc[0][cs] = __builtin_amdgcn_mfma_f32_16x16x32_bf16(afrag[0][kk], bv[cs], acc[0][cs], 0, 0, 0);
                acc[1][cs] = __builtin_amdgcn_mfma_f32_16x16x32_bf16(afrag[1][kk], bv[cs], acc[1][cs], 0, 0, 0);
            }
        }

        // fused epilogue (no cross-lane traffic; reductions deferred to writeout)
        // C/D layout: col = l15, row = quad*4 + reg
        if (ct < 16) {
            // g cols: C = ct*64 + cs*16 + l15 = h*8+d ; d = l15&7, h = ct*8 + cs*2 + (l15>>3)
            float wv[4];
            #pragma unroll
            for (int cs = 0; cs < 4; ++cs) wv[cs] = wgs[ct * 8 + cs * 2 + (l15 >> 3)];
            #pragma unroll
            for (int rs = 0; rs < 2; ++rs)
                #pragma unroll
                for (int rg = 0; rg < 4; ++rg) {
                    racc[rs * 4 + rg] += elu(acc[rs][0][rg]) * wv[0] + elu(acc[rs][1][rg]) * wv[1]
                                       + elu(acc[rs][2][rg]) * wv[2] + elu(acc[rs][3][rg]) * wv[3];
                }
        } else {
            // f cols: h = (ct-16)*64 + cs*16 + l15 (per-lane partial over its h subset)
            float wv[4];
            #pragma unroll
            for (int cs = 0; cs < 4; ++cs) wv[cs] = wfs[(ct - 16) * 64 + cs * 16 + l15];
            #pragma unroll
            for (int rs = 0; rs < 2; ++rs)
                #pragma unroll
                for (int rg = 0; rg < 4; ++rg) {
                    frac[rs * 4 + rg] += elu(acc[rs][0][rg]) * wv[0] + elu(acc[rs][1][rg]) * wv[1]
                                       + elu(acc[rs][2][rg]) * wv[2] + elu(acc[rs][3][rg]) * wv[3];
                }
        }
        __syncthreads();   // wst safe to overwrite next iter
    }

    // deferred reductions + writeout
    const float bfv = bfp[i], bgv = bgp[i];
    #pragma unroll
    for (int rs = 0; rs < 2; ++rs)
        #pragma unroll
        for (int rg = 0; rg < 4; ++rg) {
            int q = rs * 4 + rg;
            // g: lanes l15 and l15^8 hold complementary h-parity partials (same d = l15&7)
            racc[q] += __shfl_xor(racc[q], 8);
            // f: full 16-lane reduction
            float fsum = frac[q];
            fsum += __shfl_xor(fsum, 1);
            fsum += __shfl_xor(fsum, 2);
            fsum += __shfl_xor(fsum, 4);
            fsum += __shfl_xor(fsum, 8);
            int row = w * 32 + rs * 16 + quad * 4 + rg;
            size_t brow = (size_t)(b0 + row);
            if (l15 == 0)
                out[brow * 128 + i] = fsum + bfv;
            if (l15 < 8)
                out[(size_t)131072 + (brow * 128 + i) * 8 + (lane & 7)] = racc[q] + bgv;
        }
}

// ---------- fp32 fallback (only if ws too small) ----------
__global__ void sde_fallback(const float* __restrict__ x, const float* __restrict__ fw,
                             const float* __restrict__ gw,
                             const float* __restrict__ Wf, const float* __restrict__ bfp,
                             const float* __restrict__ Wg, const float* __restrict__ bgp,
                             float* __restrict__ out)
{
    __shared__ float xsh[64 * 128];
    const int t  = threadIdx.x;           // 64
    const int i  = blockIdx.x >> 4;
    const int b0 = (blockIdx.x & 15) << 6;
    for (int idx = t; idx < 64 * 128; idx += 64) xsh[idx] = x[(size_t)b0 * 128 + idx];
    __syncthreads();
    const float* xr  = &xsh[t * 128];
    const float* fwi = fw + (size_t)i * 16384;
    const float* gwi = gw + (size_t)i * 131072;
    float fa = 0.f;
    for (int h = 0; h < 128; ++h) {
        float tf = 0.f;
        for (int n = 0; n < 128; ++n) tf += xr[n] * fwi[n * 128 + h];
        fa += elu(tf) * Wf[i * 128 + h];
    }
    float ga[8];
    #pragma unroll
    for (int d = 0; d < 8; ++d) ga[d] = 0.f;
    for (int h = 0; h < 128; ++h) {
        float tg[8] = {0, 0, 0, 0, 0, 0, 0, 0};
        for (int n = 0; n < 128; ++n) {
            float xv = xr[n];
            const float* gp = gwi + ((size_t)n * 128 + h) * 8;
            #pragma unroll
            for (int d = 0; d < 8; ++d) tg[d] += xv * gp[d];
        }
        float wv = Wg[i * 128 + h];
        #pragma unroll
        for (int d = 0; d < 8; ++d) ga[d] += elu(tg[d]) * wv;
    }
    size_t b = (size_t)(b0 + t);
    out[b * 128 + i] = fa + bfp[i];
    #pragma unroll
    for (int d = 0; d < 8; ++d)
        out[(size_t)131072 + (b * 128 + i) * 8 + d] = ga[d] + bgp[i];
}

extern "C" void kernel_launch(void* const* d_in, const int* in_sizes, int n_in,
                              void* d_out, int out_size, void* d_ws, size_t ws_size,
                              hipStream_t stream) {
    const float* x  = (const float*)d_in[0];
    const float* fw = (const float*)d_in[1];
    const float* gw = (const float*)d_in[2];
    const float* Wf = (const float*)d_in[3];
    const float* bf = (const float*)d_in[4];
    const float* Wg = (const float*)d_in[5];
    const float* bg = (const float*)d_in[6];
    float* out = (float*)d_out;

    if (ws_size >= WS_NEED_BYTES) {
        u16* wsAll = (u16*)d_ws;
        sde_prepass<<<9344, 256, 0, stream>>>(fw, gw, x, wsAll);
        sde_mfma<<<1024, 256, 0, stream>>>(wsAll, Wf, bf, Wg, bg, out);
    } else {
        sde_fallback<<<2048, 64, 0, stream>>>(x, fw, gw, Wf, bf, Wg, bg, out);
    }
}